// Round 8
// baseline (1276.119 us; speedup 1.0000x reference)
//
#include <hip/hip_runtime.h>
#include <math.h>

#define D 128
#define TILE 64
#define PADX 132   // xs row stride (floats)
#define PADQ 36    // wq row stride (floats)

// ---------------- zero stats (512 f) + degree (N ints) ----------------
__global__ void zero_misc_k(float* stats, int* deg, int n) {
    int i = blockIdx.x * blockDim.x + threadIdx.x;
    if (i < 512) stats[i] = 0.f;
    if (i < n) deg[i] = 0;
}

// ---------------- K1: fused node linear (U,V,B,C) ----------------
__global__ __launch_bounds__(256, 2)
void node_linear_k(const float* __restrict__ h_in,
                   const float* __restrict__ Uw, const float* __restrict__ Ub,
                   const float* __restrict__ Vw, const float* __restrict__ Vb,
                   const float* __restrict__ Bw, const float* __restrict__ Bb,
                   const float* __restrict__ Cw, const float* __restrict__ Cb,
                   float* __restrict__ outU, float* __restrict__ outV,
                   float* __restrict__ outB, float* __restrict__ outC,
                   int M)
{
    __shared__ float xs[TILE * PADX];
    __shared__ float wsm[D * 68];
    const int tid = threadIdx.x;
    const int row0 = blockIdx.x * TILE;

    for (int f = tid; f < TILE * D / 4; f += 256) {
        int r = f >> 5, c4 = f & 31;
        int row = row0 + r;
        float4 v = make_float4(0.f, 0.f, 0.f, 0.f);
        if (row < M) v = *reinterpret_cast<const float4*>(h_in + (size_t)row * D + c4 * 4);
        *reinterpret_cast<float4*>(&xs[r * PADX + c4 * 4]) = v;
    }

    const int tx = tid & 31;
    const int ty = tid >> 5;

    const float* Ws[4] = {Uw, Vw, Bw, Cw};
    const float* Bs[4] = {Ub, Vb, Bb, Cb};
    float*       Os[4] = {outU, outV, outB, outC};

    #pragma unroll
    for (int wsel = 0; wsel < 4; ++wsel) {
        float acc[8][4];
        #pragma unroll
        for (int r = 0; r < 8; ++r)
            #pragma unroll
            for (int j = 0; j < 4; ++j) acc[r][j] = 0.f;

        const float* W = Ws[wsel];
        #pragma unroll
        for (int half = 0; half < 2; ++half) {
            __syncthreads();
            for (int f = tid; f < D * 64 / 4; f += 256) {
                int j = f >> 4, k4 = f & 15;
                float4 v = *reinterpret_cast<const float4*>(W + (size_t)j * D + half * 64 + k4 * 4);
                *reinterpret_cast<float4*>(&wsm[j * 68 + k4 * 4]) = v;
            }
            __syncthreads();
            #pragma unroll 4
            for (int k4 = 0; k4 < 16; ++k4) {
                float4 wv[4];
                #pragma unroll
                for (int jj = 0; jj < 4; ++jj)
                    wv[jj] = *reinterpret_cast<const float4*>(&wsm[(tx + 32 * jj) * 68 + k4 * 4]);
                #pragma unroll
                for (int r = 0; r < 8; ++r) {
                    float4 av = *reinterpret_cast<const float4*>(&xs[(ty * 8 + r) * PADX + half * 64 + k4 * 4]);
                    #pragma unroll
                    for (int jj = 0; jj < 4; ++jj)
                        acc[r][jj] += av.x * wv[jj].x + av.y * wv[jj].y + av.z * wv[jj].z + av.w * wv[jj].w;
                }
            }
        }
        const float* bias = Bs[wsel];
        float* O = Os[wsel];
        float bv[4];
        #pragma unroll
        for (int jj = 0; jj < 4; ++jj) bv[jj] = bias[tx + 32 * jj];
        #pragma unroll
        for (int r = 0; r < 8; ++r) {
            int row = row0 + ty * 8 + r;
            if (row < M) {
                #pragma unroll
                for (int jj = 0; jj < 4; ++jj)
                    O[(size_t)row * D + tx + 32 * jj] = acc[r][jj] + bv[jj];
            }
        }
    }
}

// ---------------- counting sort: histogram / scan / scatter ----------------
__global__ void hist_k(const int* __restrict__ dst, int* __restrict__ deg, int E) {
    for (int e = blockIdx.x * blockDim.x + threadIdx.x; e < E; e += gridDim.x * blockDim.x)
        atomicAdd(&deg[dst[e]], 1);
}

__global__ void scan_k(const int* __restrict__ deg, int* __restrict__ off,
                       int* __restrict__ cursor, int n)
{
    __shared__ int wsum[16], wpre[16];
    const int tid = threadIdx.x, lane = tid & 63, w = tid >> 6;
    int carry = 0;  // live only in thread 0
    for (int base = 0; base < n; base += 1024) {
        int i = base + tid;
        int v = (i < n) ? deg[i] : 0;
        int x = v;
        #pragma unroll
        for (int d = 1; d < 64; d <<= 1) {
            int t = __shfl_up(x, d);
            if (lane >= d) x += t;
        }
        if (lane == 63) wsum[w] = x;
        __syncthreads();
        if (tid == 0) {
            int run = carry;
            #pragma unroll
            for (int j = 0; j < 16; ++j) { int t = wsum[j]; wpre[j] = run; run += t; }
            carry = run;
        }
        __syncthreads();
        int excl = wpre[w] + x - v;
        if (i < n) { off[i] = excl; cursor[i] = excl; }
    }
    if (tid == 0) off[n] = carry;
}

__global__ void scatter_k(const int* __restrict__ dst, int* __restrict__ cursor,
                          int* __restrict__ perm, int E)
{
    for (int e = blockIdx.x * blockDim.x + threadIdx.x; e < E; e += gridDim.x * blockDim.x) {
        int pos = atomicAdd(&cursor[dst[e]], 1);
        perm[pos] = e;
    }
}

// ---------------- K2: edge kernel (GEMM + gathers + out_e + e-stats) ----------------
// No out_h atomics anymore — aggregation moved to agg_k (CSR).
__global__ __launch_bounds__(256, 3)
void edge_k(const float* __restrict__ e_in,
            const int* __restrict__ eidx,   // [2][E] int32: dst then src
            const float* __restrict__ Aw, const float* __restrict__ Ab,
            const float* __restrict__ Bh, const float* __restrict__ Ch,
            float* __restrict__ out_e,
            float* __restrict__ e_sum, float* __restrict__ e_sq,
            int E)
{
    __shared__ float xs[TILE * PADX];   // e_in tile; reused as acc transpose buffer
    __shared__ float wq[D * PADQ];      // K-quarter of Aw; reused as stats scratch

    const int tid = threadIdx.x;
    const int tx = tid & 31, ty = tid >> 5;
    const int e0 = blockIdx.x * TILE;

    int dn[8], sn[8], ev[8];
    #pragma unroll
    for (int r = 0; r < 8; ++r) {
        int e = e0 + ty * 8 + r;
        ev[r] = e;
        int ec = e < E ? e : E - 1;
        dn[r] = eidx[ec];
        sn[r] = eidx[(size_t)E + ec];
    }

    for (int f = tid; f < TILE * D / 4; f += 256) {
        int r = f >> 5, c4 = f & 31;
        int row = e0 + r; if (row >= E) row = E - 1;
        *reinterpret_cast<float4*>(&xs[r * PADX + c4 * 4]) =
            *reinterpret_cast<const float4*>(e_in + (size_t)row * D + c4 * 4);
    }
    for (int f = tid; f < D * 8; f += 256) {
        int j = f >> 3, k4 = f & 7;
        *reinterpret_cast<float4*>(&wq[j * PADQ + k4 * 4]) =
            *reinterpret_cast<const float4*>(Aw + (size_t)j * D + k4 * 4);
    }

    float acc[8][4];
    #pragma unroll
    for (int r = 0; r < 8; ++r)
        #pragma unroll
        for (int j = 0; j < 4; ++j) acc[r][j] = 0.f;

    // K-quartered GEMM
    #pragma unroll
    for (int qtr = 0; ; ++qtr) {
        __syncthreads();
        #pragma unroll 4
        for (int k4 = 0; k4 < 8; ++k4) {
            float4 wv[4];
            #pragma unroll
            for (int jj = 0; jj < 4; ++jj)
                wv[jj] = *reinterpret_cast<const float4*>(&wq[(tx + 32 * jj) * PADQ + k4 * 4]);
            #pragma unroll
            for (int r = 0; r < 8; ++r) {
                float4 av = *reinterpret_cast<const float4*>(&xs[(ty * 8 + r) * PADX + qtr * 32 + k4 * 4]);
                #pragma unroll
                for (int jj = 0; jj < 4; ++jj)
                    acc[r][jj] += av.x * wv[jj].x + av.y * wv[jj].y + av.z * wv[jj].z + av.w * wv[jj].w;
            }
        }
        if (qtr == 3) break;
        __syncthreads();
        for (int f = tid; f < D * 8; f += 256) {
            int j = f >> 3, k4 = f & 7;
            *reinterpret_cast<float4*>(&wq[j * PADQ + k4 * 4]) =
                *reinterpret_cast<const float4*>(Aw + (size_t)j * D + (qtr + 1) * 32 + k4 * 4);
        }
    }
    __syncthreads();

    // transpose acc through xs so each thread owns 4 contiguous cols
    #pragma unroll
    for (int r = 0; r < 8; ++r)
        #pragma unroll
        for (int jj = 0; jj < 4; ++jj)
            xs[(ty * 8 + r) * PADX + tx + 32 * jj] = acc[r][jj];
    __syncthreads();

    // epilogue: gather Bh/Ch (float4), combine, store out_e, stats
    float4 bias4 = *reinterpret_cast<const float4*>(Ab + 4 * tx);
    float s0 = 0.f, s1 = 0.f, s2 = 0.f, s3 = 0.f;
    float q0 = 0.f, q1 = 0.f, q2 = 0.f, q3 = 0.f;
    #pragma unroll
    for (int r = 0; r < 8; ++r) {
        if (ev[r] < E) {
            float4 gb = *reinterpret_cast<const float4*>(Bh + (size_t)dn[r] * D + 4 * tx);
            float4 gc = *reinterpret_cast<const float4*>(Ch + (size_t)sn[r] * D + 4 * tx);
            float4 a4 = *reinterpret_cast<const float4*>(&xs[(ty * 8 + r) * PADX + 4 * tx]);
            float4 pre;
            pre.x = a4.x + bias4.x + gb.x + gc.x;
            pre.y = a4.y + bias4.y + gb.y + gc.y;
            pre.z = a4.z + bias4.z + gb.z + gc.z;
            pre.w = a4.w + bias4.w + gb.w + gc.w;
            *reinterpret_cast<float4*>(out_e + (size_t)ev[r] * D + 4 * tx) = pre;
            s0 += pre.x; q0 += pre.x * pre.x;
            s1 += pre.y; q1 += pre.y * pre.y;
            s2 += pre.z; q2 += pre.z * pre.z;
            s3 += pre.w; q3 += pre.w * pre.w;
        }
    }

    s0 += __shfl_xor(s0, 32); s1 += __shfl_xor(s1, 32);
    s2 += __shfl_xor(s2, 32); s3 += __shfl_xor(s3, 32);
    q0 += __shfl_xor(q0, 32); q1 += __shfl_xor(q1, 32);
    q2 += __shfl_xor(q2, 32); q3 += __shfl_xor(q3, 32);
    float* sbuf = wq;
    float* qbuf = wq + 512;
    if ((tid & 32) == 0) {
        int w = tid >> 6;
        *reinterpret_cast<float4*>(&sbuf[w * 128 + 4 * tx]) = make_float4(s0, s1, s2, s3);
        *reinterpret_cast<float4*>(&qbuf[w * 128 + 4 * tx]) = make_float4(q0, q1, q2, q3);
    }
    __syncthreads();
    if (tid < 128) {
        float ss = sbuf[tid] + sbuf[128 + tid] + sbuf[256 + tid] + sbuf[384 + tid];
        float qq = qbuf[tid] + qbuf[128 + tid] + qbuf[256 + tid] + qbuf[384 + tid];
        unsafeAtomicAdd(&e_sum[tid], ss);
        unsafeAtomicAdd(&e_sq[tid], qq);
    }
}

// ---------------- K_agg: CSR aggregation, one wave per node + h-stats ----------------
__global__ __launch_bounds__(256)
void agg_k(const float* __restrict__ e_in, const int* __restrict__ src,
           const float* __restrict__ Vh, const int* __restrict__ off,
           const int* __restrict__ perm, float* __restrict__ out_h,
           float* __restrict__ h_sum, float* __restrict__ h_sq, int N)
{
    __shared__ float sred[4][128], qred[4][128];
    const int tid = threadIdx.x;
    const int lane = tid & 63, w = tid >> 6;
    const int node = blockIdx.x * 4 + w;

    float2 h = make_float2(0.f, 0.f);
    if (node < N) {
        const int i0 = off[node], i1 = off[node + 1];
        float2 acc = make_float2(0.f, 0.f);
        for (int i = i0; i < i1; ++i) {
            const int e = perm[i];
            const int s = src[e];
            float2 ein = *reinterpret_cast<const float2*>(e_in + (size_t)e * D + 2 * lane);
            float2 vh  = *reinterpret_cast<const float2*>(Vh  + (size_t)s * D + 2 * lane);
            acc.x += vh.x / (1.f + __expf(-ein.x));
            acc.y += vh.y / (1.f + __expf(-ein.y));
        }
        float2 uh = *reinterpret_cast<const float2*>(out_h + (size_t)node * D + 2 * lane);
        h.x = uh.x + acc.x;
        h.y = uh.y + acc.y;
        *reinterpret_cast<float2*>(out_h + (size_t)node * D + 2 * lane) = h;
    }
    sred[w][2 * lane] = h.x;      sred[w][2 * lane + 1] = h.y;
    qred[w][2 * lane] = h.x * h.x; qred[w][2 * lane + 1] = h.y * h.y;
    __syncthreads();
    if (tid < 128) {
        float ss = sred[0][tid] + sred[1][tid] + sred[2][tid] + sred[3][tid];
        float qq = qred[0][tid] + qred[1][tid] + qred[2][tid] + qred[3][tid];
        unsafeAtomicAdd(&h_sum[tid], ss);
        unsafeAtomicAdd(&h_sq[tid], qq);
    }
}

// ---------------- finalize: in-place BN + ReLU + residual (float4) ----------------
__global__ void finalize_k(const float* __restrict__ res_in,
                           float* __restrict__ out,
                           const float* __restrict__ sum, const float* __restrict__ sumsq,
                           const float* __restrict__ gamma, const float* __restrict__ beta,
                           float cntInv, int rows)
{
    const int tx = threadIdx.x & 31;
    const int rp = threadIdx.x >> 5;
    const int col4 = 4 * tx;
    float mu[4], g[4], b[4];
    #pragma unroll
    for (int i = 0; i < 4; ++i) {
        float m = sum[col4 + i] * cntInv;
        float var = sumsq[col4 + i] * cntInv - m * m;
        mu[i] = m;
        g[i] = gamma[col4 + i] * rsqrtf(var + 1e-5f);
        b[i] = beta[col4 + i];
    }
    for (int r = blockIdx.x * 8 + rp; r < rows; r += gridDim.x * 8) {
        size_t o = (size_t)r * D + col4;
        float4 x = *reinterpret_cast<const float4*>(out + o);
        float4 rr = *reinterpret_cast<const float4*>(res_in + o);
        float4 y;
        y.x = rr.x + fmaxf(g[0] * (x.x - mu[0]) + b[0], 0.f);
        y.y = rr.y + fmaxf(g[1] * (x.y - mu[1]) + b[1], 0.f);
        y.z = rr.z + fmaxf(g[2] * (x.z - mu[2]) + b[2], 0.f);
        y.w = rr.w + fmaxf(g[3] * (x.w - mu[3]) + b[3], 0.f);
        *reinterpret_cast<float4*>(out + o) = y;
    }
}

extern "C" void kernel_launch(void* const* d_in, const int* in_sizes, int n_in,
                              void* d_out, int out_size, void* d_ws, size_t ws_size,
                              hipStream_t stream)
{
    const float* h_in = (const float*)d_in[0];
    const float* e_in = (const float*)d_in[1];
    const int*   eidx = (const int*)d_in[2];
    const float* Uw = (const float*)d_in[3];  const float* Ub = (const float*)d_in[4];
    const float* Vw = (const float*)d_in[5];  const float* Vb = (const float*)d_in[6];
    const float* Aw = (const float*)d_in[7];  const float* Ab = (const float*)d_in[8];
    const float* Bw = (const float*)d_in[9];  const float* Bb = (const float*)d_in[10];
    const float* Cw = (const float*)d_in[11]; const float* Cb = (const float*)d_in[12];
    const float* hg = (const float*)d_in[13]; const float* hb = (const float*)d_in[14];
    const float* eg = (const float*)d_in[15]; const float* eb = (const float*)d_in[16];

    const int N = in_sizes[0] / D;
    const int E = in_sizes[1] / D;

    float* out_h = (float*)d_out;
    float* out_e = out_h + (size_t)N * D;

    float* ws = (float*)d_ws;
    float* Vh = ws;
    float* Bh = Vh + (size_t)N * D;
    float* Ch = Bh + (size_t)N * D;
    float* stats = Ch + (size_t)N * D;
    float* h_sum = stats;       float* h_sq = stats + 128;
    float* e_sum = stats + 256; float* e_sq = stats + 384;
    int* deg    = (int*)(stats + 512);
    int* off    = deg + N;
    int* cursor = off + N + 1;
    int* perm   = cursor + N;

    zero_misc_k<<<(N + 255) / 256, 256, 0, stream>>>(stats, deg, N);
    node_linear_k<<<(N + TILE - 1) / TILE, 256, 0, stream>>>(
        h_in, Uw, Ub, Vw, Vb, Bw, Bb, Cw, Cb, out_h, Vh, Bh, Ch, N);
    hist_k<<<1024, 256, 0, stream>>>(eidx, deg, E);
    scan_k<<<1, 1024, 0, stream>>>(deg, off, cursor, N);
    scatter_k<<<1024, 256, 0, stream>>>(eidx, cursor, perm, E);
    edge_k<<<(E + TILE - 1) / TILE, 256, 0, stream>>>(
        e_in, eidx, Aw, Ab, Bh, Ch, out_e, e_sum, e_sq, E);
    agg_k<<<(N + 3) / 4, 256, 0, stream>>>(
        e_in, eidx + E, Vh, off, perm, out_h, h_sum, h_sq, N);
    finalize_k<<<256, 256, 0, stream>>>(h_in, out_h, h_sum, h_sq, hg, hb, 1.0f / (float)N, N);
    finalize_k<<<2048, 256, 0, stream>>>(e_in, out_e, e_sum, e_sq, eg, eb, 1.0f / (float)E, E);
}

// Round 9
// 1121.730 us; speedup vs baseline: 1.1376x; 1.1376x over previous
//
#include <hip/hip_runtime.h>
#include <math.h>

#define D 128
#define TILE 64
#define PADX 132   // xs row stride (floats)
#define PADQ 36    // wq row stride (floats)

// ---------------- zero stats (512 f) + degree (N ints) ----------------
__global__ void zero_misc_k(float* stats, int* deg, int n) {
    int i = blockIdx.x * blockDim.x + threadIdx.x;
    if (i < 512) stats[i] = 0.f;
    if (i < n) deg[i] = 0;
}

// ---------------- K1: fused node linear (U,V,B,C) ----------------
__global__ __launch_bounds__(256, 2)
void node_linear_k(const float* __restrict__ h_in,
                   const float* __restrict__ Uw, const float* __restrict__ Ub,
                   const float* __restrict__ Vw, const float* __restrict__ Vb,
                   const float* __restrict__ Bw, const float* __restrict__ Bb,
                   const float* __restrict__ Cw, const float* __restrict__ Cb,
                   float* __restrict__ outU, float* __restrict__ outV,
                   float* __restrict__ outB, float* __restrict__ outC,
                   int M)
{
    __shared__ float xs[TILE * PADX];
    __shared__ float wsm[D * 68];
    const int tid = threadIdx.x;
    const int row0 = blockIdx.x * TILE;

    for (int f = tid; f < TILE * D / 4; f += 256) {
        int r = f >> 5, c4 = f & 31;
        int row = row0 + r;
        float4 v = make_float4(0.f, 0.f, 0.f, 0.f);
        if (row < M) v = *reinterpret_cast<const float4*>(h_in + (size_t)row * D + c4 * 4);
        *reinterpret_cast<float4*>(&xs[r * PADX + c4 * 4]) = v;
    }

    const int tx = tid & 31;
    const int ty = tid >> 5;

    const float* Ws[4] = {Uw, Vw, Bw, Cw};
    const float* Bs[4] = {Ub, Vb, Bb, Cb};
    float*       Os[4] = {outU, outV, outB, outC};

    #pragma unroll
    for (int wsel = 0; wsel < 4; ++wsel) {
        float acc[8][4];
        #pragma unroll
        for (int r = 0; r < 8; ++r)
            #pragma unroll
            for (int j = 0; j < 4; ++j) acc[r][j] = 0.f;

        const float* W = Ws[wsel];
        #pragma unroll
        for (int half = 0; half < 2; ++half) {
            __syncthreads();
            for (int f = tid; f < D * 64 / 4; f += 256) {
                int j = f >> 4, k4 = f & 15;
                float4 v = *reinterpret_cast<const float4*>(W + (size_t)j * D + half * 64 + k4 * 4);
                *reinterpret_cast<float4*>(&wsm[j * 68 + k4 * 4]) = v;
            }
            __syncthreads();
            #pragma unroll 4
            for (int k4 = 0; k4 < 16; ++k4) {
                float4 wv[4];
                #pragma unroll
                for (int jj = 0; jj < 4; ++jj)
                    wv[jj] = *reinterpret_cast<const float4*>(&wsm[(tx + 32 * jj) * 68 + k4 * 4]);
                #pragma unroll
                for (int r = 0; r < 8; ++r) {
                    float4 av = *reinterpret_cast<const float4*>(&xs[(ty * 8 + r) * PADX + half * 64 + k4 * 4]);
                    #pragma unroll
                    for (int jj = 0; jj < 4; ++jj)
                        acc[r][jj] += av.x * wv[jj].x + av.y * wv[jj].y + av.z * wv[jj].z + av.w * wv[jj].w;
                }
            }
        }
        const float* bias = Bs[wsel];
        float* O = Os[wsel];
        float bv[4];
        #pragma unroll
        for (int jj = 0; jj < 4; ++jj) bv[jj] = bias[tx + 32 * jj];
        #pragma unroll
        for (int r = 0; r < 8; ++r) {
            int row = row0 + ty * 8 + r;
            if (row < M) {
                #pragma unroll
                for (int jj = 0; jj < 4; ++jj)
                    O[(size_t)row * D + tx + 32 * jj] = acc[r][jj] + bv[jj];
            }
        }
    }
}

// ---------------- counting sort: histogram / scan / scatter ----------------
__global__ void hist_k(const int* __restrict__ dst, int* __restrict__ deg, int E) {
    for (int e = blockIdx.x * blockDim.x + threadIdx.x; e < E; e += gridDim.x * blockDim.x)
        atomicAdd(&deg[dst[e]], 1);
}

__global__ void scan_k(const int* __restrict__ deg, int* __restrict__ off,
                       int* __restrict__ cursor, int n)
{
    __shared__ int wsum[16], wpre[16];
    const int tid = threadIdx.x, lane = tid & 63, w = tid >> 6;
    int carry = 0;  // live only in thread 0
    for (int base = 0; base < n; base += 1024) {
        int i = base + tid;
        int v = (i < n) ? deg[i] : 0;
        int x = v;
        #pragma unroll
        for (int d = 1; d < 64; d <<= 1) {
            int t = __shfl_up(x, d);
            if (lane >= d) x += t;
        }
        if (lane == 63) wsum[w] = x;
        __syncthreads();
        if (tid == 0) {
            int run = carry;
            #pragma unroll
            for (int j = 0; j < 16; ++j) { int t = wsum[j]; wpre[j] = run; run += t; }
            carry = run;
        }
        __syncthreads();
        int excl = wpre[w] + x - v;
        if (i < n) { off[i] = excl; cursor[i] = excl; }
    }
    if (tid == 0) off[n] = carry;
}

__global__ void scatter_k(const int* __restrict__ dst, int* __restrict__ cursor,
                          int* __restrict__ perm, int E)
{
    for (int e = blockIdx.x * blockDim.x + threadIdx.x; e < E; e += gridDim.x * blockDim.x) {
        int pos = atomicAdd(&cursor[dst[e]], 1);
        perm[pos] = e;
    }
}

// ---------------- K2: edge kernel over dst-SORTED edges ----------------
// Processes edges in perm order: msg computed from the staged e_in tile
// (no re-read), runs of equal dst collapse atomics ~5x, Bh[dn] gathers
// become L1-hot. out_e is a row-scatter (512B rows).
__global__ __launch_bounds__(256, 3)
void edge_k(const float* __restrict__ e_in,
            const int* __restrict__ eidx,   // [2][E] int32: dst then src
            const int* __restrict__ perm,   // edge ids sorted by dst
            const float* __restrict__ Aw, const float* __restrict__ Ab,
            const float* __restrict__ Vh, const float* __restrict__ Bh,
            const float* __restrict__ Ch,
            float* __restrict__ out_h, float* __restrict__ out_e,
            float* __restrict__ e_sum, float* __restrict__ e_sq,
            int E)
{
    __shared__ float xs[TILE * PADX];   // gathered e_in rows (stays intact)
    __shared__ float wq[D * PADQ];      // K-quarter of Aw; reused as stats scratch
    __shared__ int eids[TILE], dns[TILE], sns[TILE];

    const int tid = threadIdx.x;
    const int tx = tid & 31, ty = tid >> 5;
    const int e0 = blockIdx.x * TILE;

    if (tid < TILE) {
        int e = e0 + tid;
        int ec = e < E ? e : E - 1;
        int eid = perm[ec];
        eids[tid] = eid;
        dns[tid] = eidx[eid];
        sns[tid] = eidx[(size_t)E + eid];
    }
    __syncthreads();

    // stage gathered e_in rows
    for (int f = tid; f < TILE * D / 4; f += 256) {
        int r = f >> 5, c4 = f & 31;
        *reinterpret_cast<float4*>(&xs[r * PADX + c4 * 4]) =
            *reinterpret_cast<const float4*>(e_in + (size_t)eids[r] * D + c4 * 4);
    }
    // stage Aw quarter 0
    for (int f = tid; f < D * 8; f += 256) {
        int j = f >> 3, k4 = f & 7;
        *reinterpret_cast<float4*>(&wq[j * PADQ + k4 * 4]) =
            *reinterpret_cast<const float4*>(Aw + (size_t)j * D + k4 * 4);
    }

    int eid8[8], dn8[8], sn8[8];
    #pragma unroll
    for (int r = 0; r < 8; ++r) {
        int row = ty * 8 + r;
        eid8[r] = eids[row]; dn8[r] = dns[row]; sn8[r] = sns[row];
    }

    float acc[8][4];
    #pragma unroll
    for (int r = 0; r < 8; ++r)
        #pragma unroll
        for (int j = 0; j < 4; ++j) acc[r][j] = 0.f;

    // K-quartered GEMM
    #pragma unroll
    for (int qtr = 0; ; ++qtr) {
        __syncthreads();
        #pragma unroll 4
        for (int k4 = 0; k4 < 8; ++k4) {
            float4 wv[4];
            #pragma unroll
            for (int jj = 0; jj < 4; ++jj)
                wv[jj] = *reinterpret_cast<const float4*>(&wq[(tx + 32 * jj) * PADQ + k4 * 4]);
            #pragma unroll
            for (int r = 0; r < 8; ++r) {
                float4 av = *reinterpret_cast<const float4*>(&xs[(ty * 8 + r) * PADX + qtr * 32 + k4 * 4]);
                #pragma unroll
                for (int jj = 0; jj < 4; ++jj)
                    acc[r][jj] += av.x * wv[jj].x + av.y * wv[jj].y + av.z * wv[jj].z + av.w * wv[jj].w;
            }
        }
        if (qtr == 3) break;
        __syncthreads();
        for (int f = tid; f < D * 8; f += 256) {
            int j = f >> 3, k4 = f & 7;
            *reinterpret_cast<float4*>(&wq[j * PADQ + k4 * 4]) =
                *reinterpret_cast<const float4*>(Aw + (size_t)j * D + (qtr + 1) * 32 + k4 * 4);
        }
    }

    // epilogue in col layout (col = tx + 32*jj); xs still holds e_in rows
    float bv[4];
    #pragma unroll
    for (int jj = 0; jj < 4; ++jj) bv[jj] = Ab[tx + 32 * jj];

    float s[4] = {0.f, 0.f, 0.f, 0.f}, q[4] = {0.f, 0.f, 0.f, 0.f};
    float rs[4] = {0.f, 0.f, 0.f, 0.f};
    #pragma unroll
    for (int r = 0; r < 8; ++r) {
        int row = ty * 8 + r;
        bool v = (e0 + row) < E;
        if (v) {
            const float* br = Bh + (size_t)dn8[r] * D;
            const float* cr = Ch + (size_t)sn8[r] * D;
            float* oe = out_e + (size_t)eid8[r] * D;
            #pragma unroll
            for (int jj = 0; jj < 4; ++jj) {
                int col = tx + 32 * jj;
                float pre = acc[r][jj] + bv[jj] + br[col] + cr[col];
                oe[col] = pre;
                s[jj] += pre;
                q[jj] += pre * pre;
            }
        }
        // gated message; zero for invalid (clamped-duplicate) rows
        const float* vr = Vh + (size_t)sn8[r] * D;
        #pragma unroll
        for (int jj = 0; jj < 4; ++jj) {
            int col = tx + 32 * jj;
            float m = v ? vr[col] / (1.f + __expf(-xs[row * PADX + col])) : 0.f;
            rs[jj] += m;
        }
        bool flush = (r == 7) || (dn8[r + 1] != dn8[r]);
        if (flush) {
            float* dst = out_h + (size_t)dn8[r] * D;
            #pragma unroll
            for (int jj = 0; jj < 4; ++jj) {
                unsafeAtomicAdd(dst + tx + 32 * jj, rs[jj]);
                rs[jj] = 0.f;
            }
        }
    }
    __syncthreads();   // all GEMM reads of wq done -> reuse as stats scratch

    // stats: lanes l and l^32 hold the same cols -> shuffle-combine,
    // then 4 per-wave partials through wq, one atomic per col per block.
    #pragma unroll
    for (int jj = 0; jj < 4; ++jj) {
        s[jj] += __shfl_xor(s[jj], 32);
        q[jj] += __shfl_xor(q[jj], 32);
    }
    float* sbuf = wq;          // 4*128
    float* qbuf = wq + 512;    // 4*128
    if ((tid & 32) == 0) {
        int w = tid >> 6;
        #pragma unroll
        for (int jj = 0; jj < 4; ++jj) {
            sbuf[w * 128 + tx + 32 * jj] = s[jj];
            qbuf[w * 128 + tx + 32 * jj] = q[jj];
        }
    }
    __syncthreads();
    if (tid < 128) {
        float ss = sbuf[tid] + sbuf[128 + tid] + sbuf[256 + tid] + sbuf[384 + tid];
        float qq = qbuf[tid] + qbuf[128 + tid] + qbuf[256 + tid] + qbuf[384 + tid];
        unsafeAtomicAdd(&e_sum[tid], ss);
        unsafeAtomicAdd(&e_sq[tid], qq);
    }
}

// ---------------- col stats over a [rows x 128] matrix (float4) ----------------
__global__ void col_stats_k(const float* __restrict__ X, int rows,
                            float* __restrict__ sum, float* __restrict__ sumsq)
{
    __shared__ float sr[8][128], qr[8][128];
    const int tx = threadIdx.x & 31;
    const int rp = threadIdx.x >> 5;
    float4 s = make_float4(0.f, 0.f, 0.f, 0.f);
    float4 q = make_float4(0.f, 0.f, 0.f, 0.f);
    for (int r = blockIdx.x * 8 + rp; r < rows; r += gridDim.x * 8) {
        float4 v = *reinterpret_cast<const float4*>(X + (size_t)r * D + 4 * tx);
        s.x += v.x; q.x += v.x * v.x;
        s.y += v.y; q.y += v.y * v.y;
        s.z += v.z; q.z += v.z * v.z;
        s.w += v.w; q.w += v.w * v.w;
    }
    *reinterpret_cast<float4*>(&sr[rp][4 * tx]) = s;
    *reinterpret_cast<float4*>(&qr[rp][4 * tx]) = q;
    __syncthreads();
    if (threadIdx.x < 128) {
        float ss = 0.f, qq = 0.f;
        #pragma unroll
        for (int t = 0; t < 8; ++t) { ss += sr[t][threadIdx.x]; qq += qr[t][threadIdx.x]; }
        unsafeAtomicAdd(&sum[threadIdx.x], ss);
        unsafeAtomicAdd(&sumsq[threadIdx.x], qq);
    }
}

// ---------------- finalize: in-place BN + ReLU + residual (float4) ----------------
__global__ void finalize_k(const float* __restrict__ res_in,
                           float* __restrict__ out,
                           const float* __restrict__ sum, const float* __restrict__ sumsq,
                           const float* __restrict__ gamma, const float* __restrict__ beta,
                           float cntInv, int rows)
{
    const int tx = threadIdx.x & 31;
    const int rp = threadIdx.x >> 5;
    const int col4 = 4 * tx;
    float mu[4], g[4], b[4];
    #pragma unroll
    for (int i = 0; i < 4; ++i) {
        float m = sum[col4 + i] * cntInv;
        float var = sumsq[col4 + i] * cntInv - m * m;
        mu[i] = m;
        g[i] = gamma[col4 + i] * rsqrtf(var + 1e-5f);
        b[i] = beta[col4 + i];
    }
    for (int r = blockIdx.x * 8 + rp; r < rows; r += gridDim.x * 8) {
        size_t o = (size_t)r * D + col4;
        float4 x = *reinterpret_cast<const float4*>(out + o);
        float4 rr = *reinterpret_cast<const float4*>(res_in + o);
        float4 y;
        y.x = rr.x + fmaxf(g[0] * (x.x - mu[0]) + b[0], 0.f);
        y.y = rr.y + fmaxf(g[1] * (x.y - mu[1]) + b[1], 0.f);
        y.z = rr.z + fmaxf(g[2] * (x.z - mu[2]) + b[2], 0.f);
        y.w = rr.w + fmaxf(g[3] * (x.w - mu[3]) + b[3], 0.f);
        *reinterpret_cast<float4*>(out + o) = y;
    }
}

extern "C" void kernel_launch(void* const* d_in, const int* in_sizes, int n_in,
                              void* d_out, int out_size, void* d_ws, size_t ws_size,
                              hipStream_t stream)
{
    const float* h_in = (const float*)d_in[0];
    const float* e_in = (const float*)d_in[1];
    const int*   eidx = (const int*)d_in[2];
    const float* Uw = (const float*)d_in[3];  const float* Ub = (const float*)d_in[4];
    const float* Vw = (const float*)d_in[5];  const float* Vb = (const float*)d_in[6];
    const float* Aw = (const float*)d_in[7];  const float* Ab = (const float*)d_in[8];
    const float* Bw = (const float*)d_in[9];  const float* Bb = (const float*)d_in[10];
    const float* Cw = (const float*)d_in[11]; const float* Cb = (const float*)d_in[12];
    const float* hg = (const float*)d_in[13]; const float* hb = (const float*)d_in[14];
    const float* eg = (const float*)d_in[15]; const float* eb = (const float*)d_in[16];

    const int N = in_sizes[0] / D;
    const int E = in_sizes[1] / D;

    float* out_h = (float*)d_out;
    float* out_e = out_h + (size_t)N * D;

    float* ws = (float*)d_ws;
    float* Vh = ws;
    float* Bh = Vh + (size_t)N * D;
    float* Ch = Bh + (size_t)N * D;
    float* stats = Ch + (size_t)N * D;
    float* h_sum = stats;       float* h_sq = stats + 128;
    float* e_sum = stats + 256; float* e_sq = stats + 384;
    int* deg    = (int*)(stats + 512);
    int* off    = deg + N;
    int* cursor = off + N + 1;
    int* perm   = cursor + N;

    zero_misc_k<<<(N + 255) / 256, 256, 0, stream>>>(stats, deg, N);
    hist_k<<<1024, 256, 0, stream>>>(eidx, deg, E);
    scan_k<<<1, 1024, 0, stream>>>(deg, off, cursor, N);
    scatter_k<<<1024, 256, 0, stream>>>(eidx, cursor, perm, E);
    node_linear_k<<<(N + TILE - 1) / TILE, 256, 0, stream>>>(
        h_in, Uw, Ub, Vw, Vb, Bw, Bb, Cw, Cb, out_h, Vh, Bh, Ch, N);
    edge_k<<<(E + TILE - 1) / TILE, 256, 0, stream>>>(
        e_in, eidx, perm, Aw, Ab, Vh, Bh, Ch, out_h, out_e, e_sum, e_sq, E);
    col_stats_k<<<256, 256, 0, stream>>>(out_h, N, h_sum, h_sq);
    finalize_k<<<256, 256, 0, stream>>>(h_in, out_h, h_sum, h_sq, hg, hb, 1.0f / (float)N, N);
    finalize_k<<<2048, 256, 0, stream>>>(e_in, out_e, e_sum, e_sq, eg, eb, 1.0f / (float)E, E);
}

// Round 10
// 1002.039 us; speedup vs baseline: 1.2735x; 1.1194x over previous
//
#include <hip/hip_runtime.h>
#include <math.h>

#define D 128
#define TILE 64
#define PADX 132   // xs row stride (floats); 528 B rows, 16B aligned, 2-way banks

typedef __attribute__((ext_vector_type(8))) short s16x8;  // 8 bf16 (4 VGPRs)
typedef __attribute__((ext_vector_type(4))) float f32x4;  // MFMA accumulator

__device__ inline ushort f32_to_bf16(float x) {
    unsigned u = __float_as_uint(x);
    return (ushort)((u + 0x7fff + ((u >> 16) & 1)) >> 16);   // RNE
}
__device__ inline float bf16_to_f32(ushort h) {
    return __uint_as_float(((unsigned)h) << 16);
}

// ---------------- zero stats (512 f) + degree (N ints) ----------------
__global__ void zero_misc_k(float* stats, int* deg, int n) {
    int i = blockIdx.x * blockDim.x + threadIdx.x;
    if (i < 512) stats[i] = 0.f;
    if (i < n) deg[i] = 0;
}

// ---------------- weight prep: Aw -> bf16 hi/lo ----------------
__global__ void wconv_k(const float* __restrict__ W, ushort* __restrict__ Wh,
                        ushort* __restrict__ Wl, int n) {
    int i = blockIdx.x * blockDim.x + threadIdx.x;
    if (i < n) {
        float x = W[i];
        ushort h = f32_to_bf16(x);
        Wh[i] = h;
        Wl[i] = f32_to_bf16(x - bf16_to_f32(h));
    }
}

// ---------------- K1: fused node linear (U,V,B,C) ----------------
__global__ __launch_bounds__(256, 2)
void node_linear_k(const float* __restrict__ h_in,
                   const float* __restrict__ Uw, const float* __restrict__ Ub,
                   const float* __restrict__ Vw, const float* __restrict__ Vb,
                   const float* __restrict__ Bw, const float* __restrict__ Bb,
                   const float* __restrict__ Cw, const float* __restrict__ Cb,
                   float* __restrict__ outU, float* __restrict__ outV,
                   float* __restrict__ outB, float* __restrict__ outC,
                   int M)
{
    __shared__ float xs[TILE * PADX];
    __shared__ float wsm[D * 68];
    const int tid = threadIdx.x;
    const int row0 = blockIdx.x * TILE;

    for (int f = tid; f < TILE * D / 4; f += 256) {
        int r = f >> 5, c4 = f & 31;
        int row = row0 + r;
        float4 v = make_float4(0.f, 0.f, 0.f, 0.f);
        if (row < M) v = *reinterpret_cast<const float4*>(h_in + (size_t)row * D + c4 * 4);
        *reinterpret_cast<float4*>(&xs[r * PADX + c4 * 4]) = v;
    }

    const int tx = tid & 31;
    const int ty = tid >> 5;

    const float* Ws[4] = {Uw, Vw, Bw, Cw};
    const float* Bs[4] = {Ub, Vb, Bb, Cb};
    float*       Os[4] = {outU, outV, outB, outC};

    #pragma unroll
    for (int wsel = 0; wsel < 4; ++wsel) {
        float acc[8][4];
        #pragma unroll
        for (int r = 0; r < 8; ++r)
            #pragma unroll
            for (int j = 0; j < 4; ++j) acc[r][j] = 0.f;

        const float* W = Ws[wsel];
        #pragma unroll
        for (int half = 0; half < 2; ++half) {
            __syncthreads();
            for (int f = tid; f < D * 64 / 4; f += 256) {
                int j = f >> 4, k4 = f & 15;
                float4 v = *reinterpret_cast<const float4*>(W + (size_t)j * D + half * 64 + k4 * 4);
                *reinterpret_cast<float4*>(&wsm[j * 68 + k4 * 4]) = v;
            }
            __syncthreads();
            #pragma unroll 4
            for (int k4 = 0; k4 < 16; ++k4) {
                float4 wv[4];
                #pragma unroll
                for (int jj = 0; jj < 4; ++jj)
                    wv[jj] = *reinterpret_cast<const float4*>(&wsm[(tx + 32 * jj) * 68 + k4 * 4]);
                #pragma unroll
                for (int r = 0; r < 8; ++r) {
                    float4 av = *reinterpret_cast<const float4*>(&xs[(ty * 8 + r) * PADX + half * 64 + k4 * 4]);
                    #pragma unroll
                    for (int jj = 0; jj < 4; ++jj)
                        acc[r][jj] += av.x * wv[jj].x + av.y * wv[jj].y + av.z * wv[jj].z + av.w * wv[jj].w;
                }
            }
        }
        const float* bias = Bs[wsel];
        float* O = Os[wsel];
        float bv[4];
        #pragma unroll
        for (int jj = 0; jj < 4; ++jj) bv[jj] = bias[tx + 32 * jj];
        #pragma unroll
        for (int r = 0; r < 8; ++r) {
            int row = row0 + ty * 8 + r;
            if (row < M) {
                #pragma unroll
                for (int jj = 0; jj < 4; ++jj)
                    O[(size_t)row * D + tx + 32 * jj] = acc[r][jj] + bv[jj];
            }
        }
    }
}

// ---------------- counting sort: histogram / scan / scatter ----------------
__global__ void hist_k(const int* __restrict__ dst, int* __restrict__ deg, int E) {
    for (int e = blockIdx.x * blockDim.x + threadIdx.x; e < E; e += gridDim.x * blockDim.x)
        atomicAdd(&deg[dst[e]], 1);
}

__global__ void scan_k(const int* __restrict__ deg, int* __restrict__ off,
                       int* __restrict__ cursor, int n)
{
    __shared__ int wsum[16], wpre[16];
    const int tid = threadIdx.x, lane = tid & 63, w = tid >> 6;
    int carry = 0;  // live only in thread 0
    for (int base = 0; base < n; base += 1024) {
        int i = base + tid;
        int v = (i < n) ? deg[i] : 0;
        int x = v;
        #pragma unroll
        for (int d = 1; d < 64; d <<= 1) {
            int t = __shfl_up(x, d);
            if (lane >= d) x += t;
        }
        if (lane == 63) wsum[w] = x;
        __syncthreads();
        if (tid == 0) {
            int run = carry;
            #pragma unroll
            for (int j = 0; j < 16; ++j) { int t = wsum[j]; wpre[j] = run; run += t; }
            carry = run;
        }
        __syncthreads();
        int excl = wpre[w] + x - v;
        if (i < n) { off[i] = excl; cursor[i] = excl; }
    }
    if (tid == 0) off[n] = carry;
}

__global__ void scatter_k(const int* __restrict__ dst, int* __restrict__ cursor,
                          int* __restrict__ perm, int E)
{
    for (int e = blockIdx.x * blockDim.x + threadIdx.x; e < E; e += gridDim.x * blockDim.x) {
        int pos = atomicAdd(&cursor[dst[e]], 1);
        perm[pos] = e;
    }
}

// ---------------- K2: edge kernel, split-fp32 MFMA GEMM ----------------
// Ae = e_in @ Aw^T via 3x mfma_f32_16x16x32_bf16 (hi/lo split, err ~2^-17).
// Sorted (perm) edge order: run-collapsed atomics, msg from staged xs tile.
// C/D frag layout (verified m89/m91): lane l, reg r -> D[(l>>4)*4+r][l&15].
__global__ __launch_bounds__(256, 3)
void edge_k(const float* __restrict__ e_in,
            const int* __restrict__ eidx,   // [2][E] int32: dst then src
            const int* __restrict__ perm,   // edge ids sorted by dst
            const ushort* __restrict__ Awh, const ushort* __restrict__ Awl,
            const float* __restrict__ Ab,
            const float* __restrict__ Vh, const float* __restrict__ Bh,
            const float* __restrict__ Ch,
            float* __restrict__ out_h, float* __restrict__ out_e,
            float* __restrict__ e_sum, float* __restrict__ e_sq,
            int E)
{
    __shared__ float xs[TILE * PADX];    // gathered e_in rows, fp32, intact throughout
    __shared__ ushort bhd[D * 32];       // Aw hi, one 32-k step, XOR-swizzled 16B chunks
    __shared__ ushort bld[D * 32];       // Aw lo
    __shared__ int eids[TILE], dns[TILE], sns[TILE];

    const int tid = threadIdx.x;
    const int w = tid >> 6;        // wave 0..3: rows w*16..w*16+15
    const int l = tid & 63;
    const int l15 = l & 15;
    const int lk = l >> 4;         // 0..3
    const int e0 = blockIdx.x * TILE;

    if (tid < TILE) {
        int e = e0 + tid;
        int ec = e < E ? e : E - 1;
        int eid = perm[ec];
        eids[tid] = eid;
        dns[tid] = eidx[eid];
        sns[tid] = eidx[(size_t)E + eid];
    }
    __syncthreads();

    // stage gathered e_in rows (fp32)
    for (int f = tid; f < TILE * D / 4; f += 256) {
        int r = f >> 5, c4 = f & 31;
        *reinterpret_cast<float4*>(&xs[r * PADX + c4 * 4]) =
            *reinterpret_cast<const float4*>(e_in + (size_t)eids[r] * D + c4 * 4);
    }
    // stage Aw hi/lo k-step 0 (swizzled: 16B chunk q -> q ^ (row&3))
    for (int f = tid; f < 512; f += 256) {
        int row = f >> 2, q = f & 3;
        int c = (q ^ (row & 3)) << 3;
        *reinterpret_cast<s16x8*>(&bhd[row * 32 + c]) =
            *reinterpret_cast<const s16x8*>(Awh + row * D + q * 8);
        *reinterpret_cast<s16x8*>(&bld[row * 32 + c]) =
            *reinterpret_cast<const s16x8*>(Awl + row * D + q * 8);
    }
    __syncthreads();

    // A-frags: lane owns row w*16+l15, k-slice lk*8 of each 32-k step; hi/lo bf16
    s16x8 ahs[4], als[4];
    {
        const int arow = w * 16 + l15;
        #pragma unroll
        for (int s = 0; s < 4; ++s) {
            f32x4 x0 = *reinterpret_cast<const f32x4*>(&xs[arow * PADX + s * 32 + lk * 8]);
            f32x4 x1 = *reinterpret_cast<const f32x4*>(&xs[arow * PADX + s * 32 + lk * 8 + 4]);
            s16x8 h, lo;
            #pragma unroll
            for (int j = 0; j < 4; ++j) {
                ushort hb = f32_to_bf16(x0[j]);
                h[j] = (short)hb;
                lo[j] = (short)f32_to_bf16(x0[j] - bf16_to_f32(hb));
                ushort hb2 = f32_to_bf16(x1[j]);
                h[j + 4] = (short)hb2;
                lo[j + 4] = (short)f32_to_bf16(x1[j] - bf16_to_f32(hb2));
            }
            ahs[s] = h; als[s] = lo;
        }
    }

    f32x4 acc[8];
    #pragma unroll
    for (int n = 0; n < 8; ++n) acc[n] = (f32x4){0.f, 0.f, 0.f, 0.f};

    #pragma unroll
    for (int s = 0; s < 4; ++s) {
        #pragma unroll
        for (int half = 0; half < 2; ++half) {
            s16x8 bh4[4], bl4[4];
            #pragma unroll
            for (int t = 0; t < 4; ++t) {
                int row = (half * 4 + t) * 16 + l15;
                int c = (lk ^ (row & 3)) << 3;
                bh4[t] = *reinterpret_cast<const s16x8*>(&bhd[row * 32 + c]);
                bl4[t] = *reinterpret_cast<const s16x8*>(&bld[row * 32 + c]);
            }
            #pragma unroll
            for (int t = 0; t < 4; ++t) {
                int n = half * 4 + t;
                acc[n] = __builtin_amdgcn_mfma_f32_16x16x32_bf16(ahs[s], bh4[t], acc[n], 0, 0, 0);
                acc[n] = __builtin_amdgcn_mfma_f32_16x16x32_bf16(ahs[s], bl4[t], acc[n], 0, 0, 0);
                acc[n] = __builtin_amdgcn_mfma_f32_16x16x32_bf16(als[s], bh4[t], acc[n], 0, 0, 0);
            }
        }
        __syncthreads();   // all frag reads of step s done
        if (s < 3) {
            for (int f = tid; f < 512; f += 256) {
                int row = f >> 2, q = f & 3;
                int c = (q ^ (row & 3)) << 3;
                *reinterpret_cast<s16x8*>(&bhd[row * 32 + c]) =
                    *reinterpret_cast<const s16x8*>(Awh + row * D + (s + 1) * 32 + q * 8);
                *reinterpret_cast<s16x8*>(&bld[row * 32 + c]) =
                    *reinterpret_cast<const s16x8*>(Awl + row * D + (s + 1) * 32 + q * 8);
            }
            __syncthreads();
        }
    }

    // epilogue in frag layout: my 4 rows = w*16 + lk*4 + r; my 8 cols = n*16 + l15
    float abv[8];
    #pragma unroll
    for (int n = 0; n < 8; ++n) abv[n] = Ab[n * 16 + l15];

    float sst[8], sq[8], rs[8];
    #pragma unroll
    for (int n = 0; n < 8; ++n) { sst[n] = 0.f; sq[n] = 0.f; rs[n] = 0.f; }

    const int mrow0 = w * 16 + lk * 4;
    #pragma unroll
    for (int r = 0; r < 4; ++r) {
        int row = mrow0 + r;
        int eid = eids[row], dn = dns[row], sn = sns[row];
        bool valid = (e0 + row) < E;
        if (valid) {
            const float* br = Bh + (size_t)dn * D;
            const float* cr = Ch + (size_t)sn * D;
            float* oe = out_e + (size_t)eid * D;
            #pragma unroll
            for (int n = 0; n < 8; ++n) {
                int col = n * 16 + l15;
                float pre = acc[n][r] + abv[n] + br[col] + cr[col];
                oe[col] = pre;
                sst[n] += pre;
                sq[n] += pre * pre;
            }
        }
        const float* vr = Vh + (size_t)sn * D;
        #pragma unroll
        for (int n = 0; n < 8; ++n) {
            int col = n * 16 + l15;
            float m = valid ? vr[col] / (1.f + __expf(-xs[row * PADX + col])) : 0.f;
            rs[n] += m;
        }
        bool flush = (r == 3) || (dns[row + 1] != dn);
        if (flush) {
            float* dst = out_h + (size_t)dn * D;
            #pragma unroll
            for (int n = 0; n < 8; ++n) {
                unsafeAtomicAdd(dst + n * 16 + l15, rs[n]);
                rs[n] = 0.f;
            }
        }
    }

    // stats: lanes l, l^16, l^32, l^48 share the same col set -> shfl reduce
    #pragma unroll
    for (int n = 0; n < 8; ++n) {
        sst[n] += __shfl_xor(sst[n], 16); sst[n] += __shfl_xor(sst[n], 32);
        sq[n]  += __shfl_xor(sq[n], 16);  sq[n]  += __shfl_xor(sq[n], 32);
    }
    float* sbuf = reinterpret_cast<float*>(bhd);   // 512 floats, b tiles dead
    float* qbuf = reinterpret_cast<float*>(bld);
    if (l < 16) {
        #pragma unroll
        for (int n = 0; n < 8; ++n) {
            sbuf[w * 128 + n * 16 + l] = sst[n];
            qbuf[w * 128 + n * 16 + l] = sq[n];
        }
    }
    __syncthreads();
    if (tid < 128) {
        float ss = sbuf[tid] + sbuf[128 + tid] + sbuf[256 + tid] + sbuf[384 + tid];
        float qq = qbuf[tid] + qbuf[128 + tid] + qbuf[256 + tid] + qbuf[384 + tid];
        unsafeAtomicAdd(&e_sum[tid], ss);
        unsafeAtomicAdd(&e_sq[tid], qq);
    }
}

// ---------------- col stats over a [rows x 128] matrix (float4) ----------------
__global__ void col_stats_k(const float* __restrict__ X, int rows,
                            float* __restrict__ sum, float* __restrict__ sumsq)
{
    __shared__ float sr[8][128], qr[8][128];
    const int tx = threadIdx.x & 31;
    const int rp = threadIdx.x >> 5;
    float4 s = make_float4(0.f, 0.f, 0.f, 0.f);
    float4 q = make_float4(0.f, 0.f, 0.f, 0.f);
    for (int r = blockIdx.x * 8 + rp; r < rows; r += gridDim.x * 8) {
        float4 v = *reinterpret_cast<const float4*>(X + (size_t)r * D + 4 * tx);
        s.x += v.x; q.x += v.x * v.x;
        s.y += v.y; q.y += v.y * v.y;
        s.z += v.z; q.z += v.z * v.z;
        s.w += v.w; q.w += v.w * v.w;
    }
    *reinterpret_cast<float4*>(&sr[rp][4 * tx]) = s;
    *reinterpret_cast<float4*>(&qr[rp][4 * tx]) = q;
    __syncthreads();
    if (threadIdx.x < 128) {
        float ss = 0.f, qq = 0.f;
        #pragma unroll
        for (int t = 0; t < 8; ++t) { ss += sr[t][threadIdx.x]; qq += qr[t][threadIdx.x]; }
        unsafeAtomicAdd(&sum[threadIdx.x], ss);
        unsafeAtomicAdd(&sumsq[threadIdx.x], qq);
    }
}

// ---------------- finalize: in-place BN + ReLU + residual (float4) ----------------
__global__ void finalize_k(const float* __restrict__ res_in,
                           float* __restrict__ out,
                           const float* __restrict__ sum, const float* __restrict__ sumsq,
                           const float* __restrict__ gamma, const float* __restrict__ beta,
                           float cntInv, int rows)
{
    const int tx = threadIdx.x & 31;
    const int rp = threadIdx.x >> 5;
    const int col4 = 4 * tx;
    float mu[4], g[4], b[4];
    #pragma unroll
    for (int i = 0; i < 4; ++i) {
        float m = sum[col4 + i] * cntInv;
        float var = sumsq[col4 + i] * cntInv - m * m;
        mu[i] = m;
        g[i] = gamma[col4 + i] * rsqrtf(var + 1e-5f);
        b[i] = beta[col4 + i];
    }
    for (int r = blockIdx.x * 8 + rp; r < rows; r += gridDim.x * 8) {
        size_t o = (size_t)r * D + col4;
        float4 x = *reinterpret_cast<const float4*>(out + o);
        float4 rr = *reinterpret_cast<const float4*>(res_in + o);
        float4 y;
        y.x = rr.x + fmaxf(g[0] * (x.x - mu[0]) + b[0], 0.f);
        y.y = rr.y + fmaxf(g[1] * (x.y - mu[1]) + b[1], 0.f);
        y.z = rr.z + fmaxf(g[2] * (x.z - mu[2]) + b[2], 0.f);
        y.w = rr.w + fmaxf(g[3] * (x.w - mu[3]) + b[3], 0.f);
        *reinterpret_cast<float4*>(out + o) = y;
    }
}

extern "C" void kernel_launch(void* const* d_in, const int* in_sizes, int n_in,
                              void* d_out, int out_size, void* d_ws, size_t ws_size,
                              hipStream_t stream)
{
    const float* h_in = (const float*)d_in[0];
    const float* e_in = (const float*)d_in[1];
    const int*   eidx = (const int*)d_in[2];
    const float* Uw = (const float*)d_in[3];  const float* Ub = (const float*)d_in[4];
    const float* Vw = (const float*)d_in[5];  const float* Vb = (const float*)d_in[6];
    const float* Aw = (const float*)d_in[7];  const float* Ab = (const float*)d_in[8];
    const float* Bw = (const float*)d_in[9];  const float* Bb = (const float*)d_in[10];
    const float* Cw = (const float*)d_in[11]; const float* Cb = (const float*)d_in[12];
    const float* hg = (const float*)d_in[13]; const float* hb = (const float*)d_in[14];
    const float* eg = (const float*)d_in[15]; const float* eb = (const float*)d_in[16];

    const int N = in_sizes[0] / D;
    const int E = in_sizes[1] / D;

    float* out_h = (float*)d_out;
    float* out_e = out_h + (size_t)N * D;

    float* ws = (float*)d_ws;
    float* Vh = ws;
    float* Bh = Vh + (size_t)N * D;
    float* Ch = Bh + (size_t)N * D;
    float* stats = Ch + (size_t)N * D;
    float* h_sum = stats;       float* h_sq = stats + 128;
    float* e_sum = stats + 256; float* e_sq = stats + 384;
    int* deg    = (int*)(stats + 512);
    int* off    = deg + N;
    int* cursor = off + N + 1;
    int* perm   = cursor + N;
    ushort* Awh = (ushort*)(perm + E);
    ushort* Awl = Awh + D * D;

    zero_misc_k<<<(N + 255) / 256, 256, 0, stream>>>(stats, deg, N);
    wconv_k<<<64, 256, 0, stream>>>(Aw, Awh, Awl, D * D);
    hist_k<<<1024, 256, 0, stream>>>(eidx, deg, E);
    scan_k<<<1, 1024, 0, stream>>>(deg, off, cursor, N);
    scatter_k<<<1024, 256, 0, stream>>>(eidx, cursor, perm, E);
    node_linear_k<<<(N + TILE - 1) / TILE, 256, 0, stream>>>(
        h_in, Uw, Ub, Vw, Vb, Bw, Bb, Cw, Cb, out_h, Vh, Bh, Ch, N);
    edge_k<<<(E + TILE - 1) / TILE, 256, 0, stream>>>(
        e_in, eidx, perm, Awh, Awl, Ab, Vh, Bh, Ch, out_h, out_e, e_sum, e_sq, E);
    col_stats_k<<<256, 256, 0, stream>>>(out_h, N, h_sum, h_sq);
    finalize_k<<<256, 256, 0, stream>>>(h_in, out_h, h_sum, h_sq, hg, hb, 1.0f / (float)N, N);
    finalize_k<<<2048, 256, 0, stream>>>(e_in, out_e, e_sum, e_sq, eg, eb, 1.0f / (float)E, E);
}

// Round 11
// 877.948 us; speedup vs baseline: 1.4535x; 1.1413x over previous
//
#include <hip/hip_runtime.h>
#include <math.h>

#define D 128
#define TILE 64
#define PADX 132   // xs row stride (floats)

typedef __attribute__((ext_vector_type(8))) short s16x8;  // 8 bf16 (4 VGPRs)
typedef __attribute__((ext_vector_type(4))) float f32x4;  // MFMA accumulator

__device__ inline ushort f32_to_bf16(float x) {
    unsigned u = __float_as_uint(x);
    return (ushort)((u + 0x7fff + ((u >> 16) & 1)) >> 16);   // RNE
}
__device__ inline float bf16_to_f32(ushort h) {
    return __uint_as_float(((unsigned)h) << 16);
}

// ---------------- zero stats (512 f) + degree (N ints) ----------------
__global__ void zero_misc_k(float* stats, int* deg, int n) {
    int i = blockIdx.x * blockDim.x + threadIdx.x;
    if (i < 512) stats[i] = 0.f;
    if (i < n) deg[i] = 0;
}

// ---------------- weight prep: pack 5 weights into MFMA B-frag layout ----------------
// For weight wsel, k-step s, col-tile t, lane l(=lk*16+l15), elem j:
//   F[((wsel*32 + s*8 + t)*64 + l)*8 + j] = W[t*16 + l15][s*32 + lk*8 + j]
// Order: 0=U 1=V 2=B 3=C 4=A.
__global__ void wconv5_k(const float* __restrict__ W0, const float* __restrict__ W1,
                         const float* __restrict__ W2, const float* __restrict__ W3,
                         const float* __restrict__ W4,
                         ushort* __restrict__ Fh, ushort* __restrict__ Fl) {
    int i = blockIdx.x * blockDim.x + threadIdx.x;
    if (i >= 5 * 16384) return;
    int wsel = i >> 14;
    int rem = i & 16383;
    int j = rem & 7;
    int l = (rem >> 3) & 63;
    int st = rem >> 9;             // s*8 + t
    int s = st >> 3, t = st & 7;
    int l15 = l & 15, lk = l >> 4;
    const float* W = wsel == 0 ? W0 : wsel == 1 ? W1 : wsel == 2 ? W2 : wsel == 3 ? W3 : W4;
    float x = W[(size_t)(t * 16 + l15) * D + s * 32 + lk * 8 + j];
    ushort h = f32_to_bf16(x);
    Fh[i] = h;
    Fl[i] = f32_to_bf16(x - bf16_to_f32(h));
}

// ---------------- K1: fused node linear (U,V,B,C) via split-bf16 MFMA ----------------
// A-frags built once from h_in (global, 64B-sector reads), reused for 4 weights.
// C/D layout (verified m89/m91): lane l, reg r -> D[(l>>4)*4+r][l&15] within 16x16 tile.
__global__ __launch_bounds__(256, 4)
void node_linear_k(const float* __restrict__ h_in,
                   const ushort* __restrict__ Fh, const ushort* __restrict__ Fl,
                   const float* __restrict__ Ub, const float* __restrict__ Vb,
                   const float* __restrict__ Bb, const float* __restrict__ Cb,
                   float* __restrict__ outU, float* __restrict__ outV,
                   float* __restrict__ outB, float* __restrict__ outC,
                   int M)
{
    const int tid = threadIdx.x;
    const int w = tid >> 6, l = tid & 63;
    const int l15 = l & 15, lk = l >> 4;
    const int row0 = blockIdx.x * TILE;

    // A-frags: lane owns row row0+w*16+l15, k-slice lk*8 of each 32-k step
    s16x8 ahs[4], als[4];
    {
        int arow = row0 + w * 16 + l15;
        if (arow >= M) arow = M - 1;
        const float* hr = h_in + (size_t)arow * D;
        #pragma unroll
        for (int s = 0; s < 4; ++s) {
            f32x4 x0 = *reinterpret_cast<const f32x4*>(hr + s * 32 + lk * 8);
            f32x4 x1 = *reinterpret_cast<const f32x4*>(hr + s * 32 + lk * 8 + 4);
            s16x8 h, lo;
            #pragma unroll
            for (int j = 0; j < 4; ++j) {
                ushort hb = f32_to_bf16(x0[j]);
                h[j] = (short)hb;
                lo[j] = (short)f32_to_bf16(x0[j] - bf16_to_f32(hb));
                ushort hb2 = f32_to_bf16(x1[j]);
                h[j + 4] = (short)hb2;
                lo[j + 4] = (short)f32_to_bf16(x1[j] - bf16_to_f32(hb2));
            }
            ahs[s] = h; als[s] = lo;
        }
    }

    const float* Bs[4] = {Ub, Vb, Bb, Cb};
    float*       Os[4] = {outU, outV, outB, outC};
    const int mrow0 = row0 + w * 16 + lk * 4;

    #pragma unroll
    for (int wsel = 0; wsel < 4; ++wsel) {
        f32x4 acc[8];
        #pragma unroll
        for (int n = 0; n < 8; ++n) acc[n] = (f32x4){0.f, 0.f, 0.f, 0.f};

        #pragma unroll
        for (int s = 0; s < 4; ++s) {
            #pragma unroll
            for (int t = 0; t < 8; ++t) {
                size_t fo = ((size_t)((wsel * 32 + s * 8 + t) * 64 + l)) * 8;
                s16x8 bh = *reinterpret_cast<const s16x8*>(Fh + fo);
                s16x8 bl = *reinterpret_cast<const s16x8*>(Fl + fo);
                acc[t] = __builtin_amdgcn_mfma_f32_16x16x32_bf16(ahs[s], bh, acc[t], 0, 0, 0);
                acc[t] = __builtin_amdgcn_mfma_f32_16x16x32_bf16(ahs[s], bl, acc[t], 0, 0, 0);
                acc[t] = __builtin_amdgcn_mfma_f32_16x16x32_bf16(als[s], bh, acc[t], 0, 0, 0);
            }
        }

        const float* bias = Bs[wsel];
        float* O = Os[wsel];
        float bv[8];
        #pragma unroll
        for (int n = 0; n < 8; ++n) bv[n] = bias[n * 16 + l15];
        #pragma unroll
        for (int r = 0; r < 4; ++r) {
            int row = mrow0 + r;
            if (row < M) {
                float* orow = O + (size_t)row * D;
                #pragma unroll
                for (int n = 0; n < 8; ++n)
                    orow[n * 16 + l15] = acc[n][r] + bv[n];
            }
        }
    }
}

// ---------------- counting sort: histogram / scan / scatter ----------------
__global__ void hist_k(const int* __restrict__ dst, int* __restrict__ deg, int E) {
    for (int e = blockIdx.x * blockDim.x + threadIdx.x; e < E; e += gridDim.x * blockDim.x)
        atomicAdd(&deg[dst[e]], 1);
}

__global__ void scan_k(const int* __restrict__ deg, int* __restrict__ off,
                       int* __restrict__ cursor, int n)
{
    __shared__ int wsum[16], wpre[16];
    const int tid = threadIdx.x, lane = tid & 63, w = tid >> 6;
    int carry = 0;  // live only in thread 0
    for (int base = 0; base < n; base += 1024) {
        int i = base + tid;
        int v = (i < n) ? deg[i] : 0;
        int x = v;
        #pragma unroll
        for (int d = 1; d < 64; d <<= 1) {
            int t = __shfl_up(x, d);
            if (lane >= d) x += t;
        }
        if (lane == 63) wsum[w] = x;
        __syncthreads();
        if (tid == 0) {
            int run = carry;
            #pragma unroll
            for (int j = 0; j < 16; ++j) { int t = wsum[j]; wpre[j] = run; run += t; }
            carry = run;
        }
        __syncthreads();
        int excl = wpre[w] + x - v;
        if (i < n) { off[i] = excl; cursor[i] = excl; }
    }
    if (tid == 0) off[n] = carry;
}

__global__ void scatter_k(const int* __restrict__ dst, int* __restrict__ cursor,
                          int* __restrict__ perm, int E)
{
    for (int e = blockIdx.x * blockDim.x + threadIdx.x; e < E; e += gridDim.x * blockDim.x) {
        int pos = atomicAdd(&cursor[dst[e]], 1);
        perm[pos] = e;
    }
}

// ---------------- K2: edge kernel, split-bf16 MFMA, B-frags from global ----------------
__global__ __launch_bounds__(256, 4)
void edge_k(const float* __restrict__ e_in,
            const int* __restrict__ eidx,   // [2][E] int32: dst then src
            const int* __restrict__ perm,   // edge ids sorted by dst
            const ushort* __restrict__ AFh, const ushort* __restrict__ AFl,  // A-weight frags
            const float* __restrict__ Ab,
            const float* __restrict__ Vh, const float* __restrict__ Bh,
            const float* __restrict__ Ch,
            float* __restrict__ out_h, float* __restrict__ out_e,
            float* __restrict__ e_sum, float* __restrict__ e_sq,
            int E)
{
    __shared__ float xs[TILE * PADX];    // gathered e_in rows, fp32, intact throughout
    __shared__ float sbuf[512], qbuf[512];
    __shared__ int eids[TILE], dns[TILE], sns[TILE];

    const int tid = threadIdx.x;
    const int w = tid >> 6;
    const int l = tid & 63;
    const int l15 = l & 15;
    const int lk = l >> 4;
    const int e0 = blockIdx.x * TILE;

    if (tid < TILE) {
        int e = e0 + tid;
        int ec = e < E ? e : E - 1;
        int eid = perm[ec];
        eids[tid] = eid;
        dns[tid] = eidx[eid];
        sns[tid] = eidx[(size_t)E + eid];
    }
    __syncthreads();

    // stage gathered e_in rows (fp32)
    for (int f = tid; f < TILE * D / 4; f += 256) {
        int r = f >> 5, c4 = f & 31;
        *reinterpret_cast<float4*>(&xs[r * PADX + c4 * 4]) =
            *reinterpret_cast<const float4*>(e_in + (size_t)eids[r] * D + c4 * 4);
    }
    __syncthreads();

    // A-frags from xs
    s16x8 ahs[4], als[4];
    {
        const int arow = w * 16 + l15;
        #pragma unroll
        for (int s = 0; s < 4; ++s) {
            f32x4 x0 = *reinterpret_cast<const f32x4*>(&xs[arow * PADX + s * 32 + lk * 8]);
            f32x4 x1 = *reinterpret_cast<const f32x4*>(&xs[arow * PADX + s * 32 + lk * 8 + 4]);
            s16x8 h, lo;
            #pragma unroll
            for (int j = 0; j < 4; ++j) {
                ushort hb = f32_to_bf16(x0[j]);
                h[j] = (short)hb;
                lo[j] = (short)f32_to_bf16(x0[j] - bf16_to_f32(hb));
                ushort hb2 = f32_to_bf16(x1[j]);
                h[j + 4] = (short)hb2;
                lo[j + 4] = (short)f32_to_bf16(x1[j] - bf16_to_f32(hb2));
            }
            ahs[s] = h; als[s] = lo;
        }
    }

    f32x4 acc[8];
    #pragma unroll
    for (int n = 0; n < 8; ++n) acc[n] = (f32x4){0.f, 0.f, 0.f, 0.f};

    #pragma unroll
    for (int s = 0; s < 4; ++s) {
        #pragma unroll
        for (int t = 0; t < 8; ++t) {
            size_t fo = ((size_t)((s * 8 + t) * 64 + l)) * 8;
            s16x8 bh = *reinterpret_cast<const s16x8*>(AFh + fo);
            s16x8 bl = *reinterpret_cast<const s16x8*>(AFl + fo);
            acc[t] = __builtin_amdgcn_mfma_f32_16x16x32_bf16(ahs[s], bh, acc[t], 0, 0, 0);
            acc[t] = __builtin_amdgcn_mfma_f32_16x16x32_bf16(ahs[s], bl, acc[t], 0, 0, 0);
            acc[t] = __builtin_amdgcn_mfma_f32_16x16x32_bf16(als[s], bh, acc[t], 0, 0, 0);
        }
    }

    // epilogue in frag layout: my 4 rows = w*16 + lk*4 + r; my 8 cols = n*16 + l15
    float abv[8];
    #pragma unroll
    for (int n = 0; n < 8; ++n) abv[n] = Ab[n * 16 + l15];

    float sst[8], sq[8], rs[8];
    #pragma unroll
    for (int n = 0; n < 8; ++n) { sst[n] = 0.f; sq[n] = 0.f; rs[n] = 0.f; }

    const int mrow0 = w * 16 + lk * 4;
    #pragma unroll
    for (int r = 0; r < 4; ++r) {
        int row = mrow0 + r;
        int eid = eids[row], dn = dns[row], sn = sns[row];
        bool valid = (e0 + row) < E;
        if (valid) {
            const float* br = Bh + (size_t)dn * D;
            const float* cr = Ch + (size_t)sn * D;
            float* oe = out_e + (size_t)eid * D;
            #pragma unroll
            for (int n = 0; n < 8; ++n) {
                int col = n * 16 + l15;
                float pre = acc[n][r] + abv[n] + br[col] + cr[col];
                oe[col] = pre;
                sst[n] += pre;
                sq[n] += pre * pre;
            }
        }
        const float* vr = Vh + (size_t)sn * D;
        #pragma unroll
        for (int n = 0; n < 8; ++n) {
            int col = n * 16 + l15;
            float m = valid ? vr[col] / (1.f + __expf(-xs[row * PADX + col])) : 0.f;
            rs[n] += m;
        }
        bool flush = (r == 3) || (dns[row + 1] != dn);
        if (flush) {
            float* dst = out_h + (size_t)dn * D;
            #pragma unroll
            for (int n = 0; n < 8; ++n) {
                unsafeAtomicAdd(dst + n * 16 + l15, rs[n]);
                rs[n] = 0.f;
            }
        }
    }

    // stats: lanes l, l^16, l^32, l^48 share the same col set -> shfl reduce
    #pragma unroll
    for (int n = 0; n < 8; ++n) {
        sst[n] += __shfl_xor(sst[n], 16); sst[n] += __shfl_xor(sst[n], 32);
        sq[n]  += __shfl_xor(sq[n], 16);  sq[n]  += __shfl_xor(sq[n], 32);
    }
    if (l < 16) {
        #pragma unroll
        for (int n = 0; n < 8; ++n) {
            sbuf[w * 128 + n * 16 + l] = sst[n];
            qbuf[w * 128 + n * 16 + l] = sq[n];
        }
    }
    __syncthreads();
    if (tid < 128) {
        float ss = sbuf[tid] + sbuf[128 + tid] + sbuf[256 + tid] + sbuf[384 + tid];
        float qq = qbuf[tid] + qbuf[128 + tid] + qbuf[256 + tid] + qbuf[384 + tid];
        unsafeAtomicAdd(&e_sum[tid], ss);
        unsafeAtomicAdd(&e_sq[tid], qq);
    }
}

// ---------------- col stats over a [rows x 128] matrix (float4) ----------------
__global__ void col_stats_k(const float* __restrict__ X, int rows,
                            float* __restrict__ sum, float* __restrict__ sumsq)
{
    __shared__ float sr[8][128], qr[8][128];
    const int tx = threadIdx.x & 31;
    const int rp = threadIdx.x >> 5;
    float4 s = make_float4(0.f, 0.f, 0.f, 0.f);
    float4 q = make_float4(0.f, 0.f, 0.f, 0.f);
    for (int r = blockIdx.x * 8 + rp; r < rows; r += gridDim.x * 8) {
        float4 v = *reinterpret_cast<const float4*>(X + (size_t)r * D + 4 * tx);
        s.x += v.x; q.x += v.x * v.x;
        s.y += v.y; q.y += v.y * v.y;
        s.z += v.z; q.z += v.z * v.z;
        s.w += v.w; q.w += v.w * v.w;
    }
    *reinterpret_cast<float4*>(&sr[rp][4 * tx]) = s;
    *reinterpret_cast<float4*>(&qr[rp][4 * tx]) = q;
    __syncthreads();
    if (threadIdx.x < 128) {
        float ss = 0.f, qq = 0.f;
        #pragma unroll
        for (int t = 0; t < 8; ++t) { ss += sr[t][threadIdx.x]; qq += qr[t][threadIdx.x]; }
        unsafeAtomicAdd(&sum[threadIdx.x], ss);
        unsafeAtomicAdd(&sumsq[threadIdx.x], qq);
    }
}

// ---------------- finalize: in-place BN + ReLU + residual (float4) ----------------
__global__ void finalize_k(const float* __restrict__ res_in,
                           float* __restrict__ out,
                           const float* __restrict__ sum, const float* __restrict__ sumsq,
                           const float* __restrict__ gamma, const float* __restrict__ beta,
                           float cntInv, int rows)
{
    const int tx = threadIdx.x & 31;
    const int rp = threadIdx.x >> 5;
    const int col4 = 4 * tx;
    float mu[4], g[4], b[4];
    #pragma unroll
    for (int i = 0; i < 4; ++i) {
        float m = sum[col4 + i] * cntInv;
        float var = sumsq[col4 + i] * cntInv - m * m;
        mu[i] = m;
        g[i] = gamma[col4 + i] * rsqrtf(var + 1e-5f);
        b[i] = beta[col4 + i];
    }
    for (int r = blockIdx.x * 8 + rp; r < rows; r += gridDim.x * 8) {
        size_t o = (size_t)r * D + col4;
        float4 x = *reinterpret_cast<const float4*>(out + o);
        float4 rr = *reinterpret_cast<const float4*>(res_in + o);
        float4 y;
        y.x = rr.x + fmaxf(g[0] * (x.x - mu[0]) + b[0], 0.f);
        y.y = rr.y + fmaxf(g[1] * (x.y - mu[1]) + b[1], 0.f);
        y.z = rr.z + fmaxf(g[2] * (x.z - mu[2]) + b[2], 0.f);
        y.w = rr.w + fmaxf(g[3] * (x.w - mu[3]) + b[3], 0.f);
        *reinterpret_cast<float4*>(out + o) = y;
    }
}

extern "C" void kernel_launch(void* const* d_in, const int* in_sizes, int n_in,
                              void* d_out, int out_size, void* d_ws, size_t ws_size,
                              hipStream_t stream)
{
    const float* h_in = (const float*)d_in[0];
    const float* e_in = (const float*)d_in[1];
    const int*   eidx = (const int*)d_in[2];
    const float* Uw = (const float*)d_in[3];  const float* Ub = (const float*)d_in[4];
    const float* Vw = (const float*)d_in[5];  const float* Vb = (const float*)d_in[6];
    const float* Aw = (const float*)d_in[7];  const float* Ab = (const float*)d_in[8];
    const float* Bw = (const float*)d_in[9];  const float* Bb = (const float*)d_in[10];
    const float* Cw = (const float*)d_in[11]; const float* Cb = (const float*)d_in[12];
    const float* hg = (const float*)d_in[13]; const float* hb = (const float*)d_in[14];
    const float* eg = (const float*)d_in[15]; const float* eb = (const float*)d_in[16];

    const int N = in_sizes[0] / D;
    const int E = in_sizes[1] / D;

    float* out_h = (float*)d_out;
    float* out_e = out_h + (size_t)N * D;

    float* ws = (float*)d_ws;
    float* Vh = ws;
    float* Bh = Vh + (size_t)N * D;
    float* Ch = Bh + (size_t)N * D;
    float* stats = Ch + (size_t)N * D;
    float* h_sum = stats;       float* h_sq = stats + 128;
    float* e_sum = stats + 256; float* e_sq = stats + 384;
    int* deg    = (int*)(stats + 512);
    int* off    = deg + N;
    int* cursor = off + N + 1;
    int* perm   = cursor + N;
    ushort* Fh = (ushort*)(perm + E);        // 5*16384 ushort
    ushort* Fl = Fh + 5 * 16384;

    zero_misc_k<<<(N + 255) / 256, 256, 0, stream>>>(stats, deg, N);
    wconv5_k<<<(5 * 16384 + 255) / 256, 256, 0, stream>>>(Uw, Vw, Bw, Cw, Aw, Fh, Fl);
    hist_k<<<1024, 256, 0, stream>>>(eidx, deg, E);
    scan_k<<<1, 1024, 0, stream>>>(deg, off, cursor, N);
    scatter_k<<<1024, 256, 0, stream>>>(eidx, cursor, perm, E);
    node_linear_k<<<(N + TILE - 1) / TILE, 256, 0, stream>>>(
        h_in, Fh, Fl, Ub, Vb, Bb, Cb, out_h, Vh, Bh, Ch, N);
    edge_k<<<(E + TILE - 1) / TILE, 256, 0, stream>>>(
        e_in, eidx, perm, Fh + 4 * 16384, Fl + 4 * 16384, Ab, Vh, Bh, Ch,
        out_h, out_e, e_sum, e_sq, E);
    col_stats_k<<<256, 256, 0, stream>>>(out_h, N, h_sum, h_sq);
    finalize_k<<<256, 256, 0, stream>>>(h_in, out_h, h_sum, h_sq, hg, hb, 1.0f / (float)N, N);
    finalize_k<<<2048, 256, 0, stream>>>(e_in, out_e, e_sum, e_sq, eg, eb, 1.0f / (float)E, E);
}